// Round 3
// baseline (375.877 us; speedup 1.0000x reference)
//
#include <hip/hip_runtime.h>
#include <math.h>

// Problem constants: B=8, C=64, H=W=64, O=64, K=3, KK=9, HW=4096
// ws layout (floats):
//   [0, 36864)         Wt[(c*9+k)*64 + o]    = weight[o][c][k]      (transposed)
//   [36864, 69120)     OWtP[(cg*9+t)*28+oc]  = om_weight[oc][cg][t] (transposed,
//                                              oc padded 27->28 for float4)
//   [131072, +3538944) omp[q][b][27][4096]   om-conv partials, q = ci-quarter
#define WT_OFF   0
#define OWT_OFF  36864
#define OMP_OFF  131072

__global__ __launch_bounds__(256) void prep_kernel(
    const float* __restrict__ weight, const float* __restrict__ om_weight,
    float* __restrict__ ws)
{
    int idx = blockIdx.x * 256 + threadIdx.x;   // grid covers exactly 69120
    if (idx < 36864) {
        int o = idx & 63;
        int ck = idx >> 6;
        int c = ck / 9;
        int k = ck - c * 9;
        ws[WT_OFF + idx] = weight[(o * 64 + c) * 9 + k];
    } else {
        int e = idx - 36864;          // < 32256
        int oc = e % 28;
        int r  = e / 28;              // r = cg*9 + t, < 1152
        int cg = r / 9;
        int t  = r - cg * 9;
        ws[OWT_OFF + e] = (oc < 27) ? om_weight[(oc * 128 + cg) * 9 + t] : 0.f;
    }
}

// om = conv2d(concat(feat, deg), om_weight) as 4 partial sums over input-
// channel quarters. One thread per (quarter, pixel); lane = w. Weights are
// delivered as uniform-address VECTOR float4 loads (asm-zero forces VMEM;
// the scalar path stalled on SGPR pressure + scalar-L1 thrash in round 2).
__global__ __launch_bounds__(256) void omconv_kernel(
    const float* __restrict__ feat, const float* __restrict__ deg,
    const float* __restrict__ ws_c, float* __restrict__ omp)
{
    int zero;
    asm volatile("v_mov_b32 %0, 0" : "=v"(zero));   // opaque 0 in a VGPR

    const int q   = blockIdx.x >> 7;                          // 0..3
    const int pix = (blockIdx.x & 127) * 256 + threadIdx.x;   // 0..32767
    const int b = pix >> 12;
    const int h = (pix >> 6) & 63;
    const int w = pix & 63;
    const float* src = (q < 2) ? feat : deg;
    const int c0 = (q & 1) * 32;
    const float4* OW4 = (const float4*)(ws_c + OWT_OFF);

    float acc[28];
#pragma unroll
    for (int i = 0; i < 28; i++) acc[i] = 0.f;

    for (int i = 0; i < 32; i++) {
        const int c  = c0 + i;
        const int cg = q * 32 + i;
        const float* sp = src + (b * 64 + c) * 4096;
        float v[9];
#pragma unroll
        for (int t = 0; t < 9; t++) {
            int ky = t / 3, kx = t - (t / 3) * 3;
            int y = h - 1 + ky, x = w - 1 + kx;
            bool ok = (y >= 0) & (y < 64) & (x >= 0) & (x < 64);
            v[t] = ok ? sp[y * 64 + x] : 0.f;
        }
        const float4* wp = OW4 + cg * 63;   // 9t * 28oc = 63 float4 per cg
#pragma unroll
        for (int t = 0; t < 9; t++) {
#pragma unroll
            for (int j = 0; j < 7; j++) {
                float4 w4 = wp[t * 7 + j + zero];
                acc[j * 4 + 0] = fmaf(v[t], w4.x, acc[j * 4 + 0]);
                acc[j * 4 + 1] = fmaf(v[t], w4.y, acc[j * 4 + 1]);
                acc[j * 4 + 2] = fmaf(v[t], w4.z, acc[j * 4 + 2]);
                acc[j * 4 + 3] = fmaf(v[t], w4.w, acc[j * 4 + 3]);
            }
        }
    }

    float* dst = omp + ((q * 8 + b) * 27) * 4096 + h * 64 + w;
#pragma unroll
    for (int oc = 0; oc < 27; oc++) dst[oc * 4096] = acc[oc];
}

// Deformable conv. One block per (b, h) row; lane = w; 4 waves split the 64
// input channels 16 each. Weights via uniform-address float4 VMEM loads
// (vmcnt-pipelined). Gathers and sampling unchanged from round 2 (verified).
__global__ __launch_bounds__(256) void deform_kernel(
    const float* __restrict__ feat, const float* __restrict__ om_bias,
    const float* __restrict__ ws_c, float* __restrict__ out)
{
    __shared__ float red[4096];
    int zero;
    asm volatile("v_mov_b32 %0, 0" : "=v"(zero));   // opaque 0 in a VGPR

    const int b = blockIdx.x >> 6;
    const int h = blockIdx.x & 63;
    const int w = threadIdx.x & 63;
    const int wv = __builtin_amdgcn_readfirstlane(threadIdx.x >> 6); // 0..3
    const float* Wt  = ws_c + WT_OFF;
    const float* omp = ws_c + OMP_OFF;
    const int hw = h * 64 + w;

    float W00[9], W01[9], W10[9], W11[9];
    int   A00[9], A01[9], A10[9], A11[9];
#pragma unroll
    for (int k = 0; k < 9; k++) {
        float dy = om_bias[2 * k];
        float dx = om_bias[2 * k + 1];
        float mm = om_bias[18 + k];
#pragma unroll
        for (int q = 0; q < 4; q++) {
            const float* p = omp + ((q * 8 + b) * 27) * 4096 + hw;
            dy += p[(2 * k) * 4096];
            dx += p[(2 * k + 1) * 4096];
            mm += p[(18 + k) * 4096];
        }
        mm = 1.f / (1.f + __expf(-mm));   // sigmoid(mask)
        float yy = (float)(h - 1 + k / 3) + dy;
        float xx = (float)(w - 1 + (k - (k / 3) * 3)) + dx;
        float fy = floorf(yy), fx = floorf(xx);
        int y0 = (int)fy, x0 = (int)fx;
        float wy = yy - fy, wx = xx - fx;
        bool vy0 = (y0 >= 0) & (y0 < 64);
        bool vy1 = (y0 >= -1) & (y0 < 63);
        bool vx0 = (x0 >= 0) & (x0 < 64);
        bool vx1 = (x0 >= -1) & (x0 < 63);
        float a0 = (1.f - wy) * mm, a1 = wy * mm;
        W00[k] = a0 * (1.f - wx) * (float)(vy0 & vx0);
        W01[k] = a0 * wx         * (float)(vy0 & vx1);
        W10[k] = a1 * (1.f - wx) * (float)(vy1 & vx0);
        W11[k] = a1 * wx         * (float)(vy1 & vx1);
        // Each tap index clamped INDEPENDENTLY (clamp(y0+1), not clamp(y0)+1)
        int iy0 = min(max(y0, 0), 63),     ix0 = min(max(x0, 0), 63);
        int iy1 = min(max(y0 + 1, 0), 63), ix1 = min(max(x0 + 1, 0), 63);
        A00[k] = iy0 * 64 + ix0;  A01[k] = iy0 * 64 + ix1;
        A10[k] = iy1 * 64 + ix0;  A11[k] = iy1 * 64 + ix1;
    }

    float acc[64];
#pragma unroll
    for (int o = 0; o < 64; o++) acc[o] = 0.f;

    for (int ci = 0; ci < 16; ci++) {
        const int c = wv * 16 + ci;   // scalar (wv from readfirstlane)
        const float* sp = feat + (b * 64 + c) * 4096;
        float s[9];
#pragma unroll
        for (int k = 0; k < 9; k++) {
            s[k] = W00[k] * sp[A00[k]] + W01[k] * sp[A01[k]]
                 + W10[k] * sp[A10[k]] + W11[k] * sp[A11[k]];
        }
        const float4* wc4 = (const float4*)(Wt + c * 576);  // 144 float4
#pragma unroll
        for (int k = 0; k < 9; k++) {
#pragma unroll
            for (int o4 = 0; o4 < 16; o4++) {
                float4 w4 = wc4[k * 16 + o4 + zero];
                acc[o4 * 4 + 0] = fmaf(s[k], w4.x, acc[o4 * 4 + 0]);
                acc[o4 * 4 + 1] = fmaf(s[k], w4.y, acc[o4 * 4 + 1]);
                acc[o4 * 4 + 2] = fmaf(s[k], w4.z, acc[o4 * 4 + 2]);
                acc[o4 * 4 + 3] = fmaf(s[k], w4.w, acc[o4 * 4 + 3]);
            }
        }
    }

    // reduce the 4 wave partials (lane = w, 64 o's) through LDS
    for (int r = 0; r < 4; r++) {
        if (wv == r) {
            if (r == 0) {
#pragma unroll
                for (int o = 0; o < 64; o++) red[o * 64 + w] = acc[o];
            } else {
#pragma unroll
                for (int o = 0; o < 64; o++) red[o * 64 + w] += acc[o];
            }
        }
        __syncthreads();
    }

    float* ob = out + (b * 64) * 4096 + h * 64;
#pragma unroll
    for (int j = 0; j < 16; j++) {
        int idx = j * 256 + threadIdx.x;
        int o = idx >> 6, ww = idx & 63;
        ob[o * 4096 + ww] = red[idx];
    }
}

extern "C" void kernel_launch(void* const* d_in, const int* in_sizes, int n_in,
                              void* d_out, int out_size, void* d_ws, size_t ws_size,
                              hipStream_t stream)
{
    const float* feat      = (const float*)d_in[0];
    const float* deg       = (const float*)d_in[1];
    const float* weight    = (const float*)d_in[2];
    const float* om_weight = (const float*)d_in[3];
    const float* om_bias   = (const float*)d_in[4];
    float* out = (float*)d_out;
    float* ws  = (float*)d_ws;

    hipLaunchKernelGGL(prep_kernel,   dim3(270), dim3(256), 0, stream,
                       weight, om_weight, ws);
    hipLaunchKernelGGL(omconv_kernel, dim3(512), dim3(256), 0, stream,
                       feat, deg, ws, ws + OMP_OFF);
    hipLaunchKernelGGL(deform_kernel, dim3(512), dim3(256), 0, stream,
                       feat, om_bias, ws, out);
}

// Round 4
// 180.474 us; speedup vs baseline: 2.0827x; 2.0827x over previous
//
#include <hip/hip_runtime.h>
#include <math.h>

// B=8, C=64, H=W=64, O=64, K=3, KK=9, HW=4096
// MFMA formulation (bf16 in, fp32 acc), mfma_f32_16x16x32_bf16:
//   deform: out[b][o][hw]  = sum_{k=0..575}  Wd[o][k]  * S[k][hw]   (per b)
//   omconv: om[b][oc][hw]  = sum_{k=0..1151} Wo[oc][k] * P[k][hw]   (per b)
// K-index ordering (both): K_A = (cg>>5)*288 + t*32 + (cg&31); contraction
// runs in 288-chunks so the LDS B-tile is 288x64 bf16 = 36.9 KB (<64KB).
//
// ws layout (bytes):
//   [0,      73728)  Wd bf16[64][576]    = weight[o][c][t] reordered
//   [73728, 147456)  Wo bf16[32][1152]   = om_weight[oc][cg][t] reordered,
//                                          oc rows 27..31 zero-padded
//   [147456, ...)    om  fp32[8][27][4096]  om-conv output (no bias)
#define WD_SHORT_OFF 0
#define WO_SHORT_OFF 36864
#define OM_FLOAT_OFF 36864   // in floats: byte 147456

typedef short  short8  __attribute__((ext_vector_type(8)));
typedef float  float4v __attribute__((ext_vector_type(4)));

static __device__ __forceinline__ short f2bf(float f) {
    unsigned int u = __builtin_bit_cast(unsigned int, f);
    u += 0x7FFFu + ((u >> 16) & 1u);   // round-to-nearest-even
    return (short)(u >> 16);
}

__global__ __launch_bounds__(256) void prep_kernel(
    const float* __restrict__ weight, const float* __restrict__ om_weight,
    short* __restrict__ wd, short* __restrict__ wo)
{
    int idx = blockIdx.x * 256 + threadIdx.x;   // grid covers exactly 73728
    if (idx < 36864) {
        int o = idx / 576, r = idx % 576;
        int ch = r / 288, rr = r % 288;
        int t = rr >> 5, c = ch * 32 + (rr & 31);
        wd[idx] = f2bf(weight[(o * 64 + c) * 9 + t]);
    } else {
        int e = idx - 36864;
        int ocp = e / 1152, r = e % 1152;
        int q = r / 288, rr = r % 288;
        int t = rr >> 5, cg = q * 32 + (rr & 31);
        wo[e] = (ocp < 27) ? f2bf(om_weight[(ocp * 128 + cg) * 9 + t])
                           : (short)0;
    }
}

// om conv via MFMA. Block = (b,h) row, 4 waves. Wave roles: ms=wv&1 is the
// 16-row oc strip, nh=wv>>1 is the 32-col pixel half. 4 K-chunks of 288
// (feat c0..31, feat c32..63, deg c0..31, deg c32..63).
__global__ __launch_bounds__(256) void omconv_mfma(
    const float* __restrict__ feat, const float* __restrict__ deg,
    const short* __restrict__ wo, float* __restrict__ om)
{
    __shared__ short8 S[2304];                 // [g=0..35][w=0..63]
    const int b = blockIdx.x >> 6, h = blockIdx.x & 63;
    const int lane = threadIdx.x & 63;
    const int wv   = threadIdx.x >> 6;
    const int l16 = lane & 15, lq = lane >> 4;
    const int ms = wv & 1, nh = wv >> 1;
    const int w = lane;

    float4v acc[2];
    acc[0] = (float4v){0.f, 0.f, 0.f, 0.f};
    acc[1] = (float4v){0.f, 0.f, 0.f, 0.f};

    for (int quarter = 0; quarter < 4; quarter++) {
        const float* src = (quarter >= 2) ? deg : feat;
        // this wave stages channels cbase..cbase+7 (local to src tensor)
        const float* sp = src + (b * 64 + (quarter & 1) * 32 + wv * 8) * 4096;
#pragma unroll
        for (int t = 0; t < 9; t++) {
            const int ky = t / 3, kx = t - ky * 3;
            int y = h - 1 + ky, x = w - 1 + kx;
            bool ok = (y >= 0) & (y < 64) & (x >= 0) & (x < 64);
            int off = min(max(y, 0), 63) * 64 + min(max(x, 0), 63);
            short8 pk;
#pragma unroll
            for (int cc = 0; cc < 8; cc++) {
                float v = sp[cc * 4096 + off];
                pk[cc] = f2bf(ok ? v : 0.f);
            }
            S[(t * 4 + wv) * 64 + w] = pk;
        }
        // A-frags for this chunk (before barrier: overlaps others' staging)
        const short* Ap = wo + (ms * 16 + l16) * 1152 + quarter * 288 + lq * 8;
        short8 afr[9];
#pragma unroll
        for (int kb = 0; kb < 9; kb++)
            afr[kb] = *(const short8*)(Ap + kb * 32);
        __syncthreads();
#pragma unroll
        for (int kb = 0; kb < 9; kb++) {
#pragma unroll
            for (int nt = 0; nt < 2; nt++) {
                short8 bfr = S[(kb * 4 + lq) * 64 + (nh * 32 + nt * 16 + l16)];
                acc[nt] = __builtin_amdgcn_mfma_f32_16x16x32_bf16(
                    afr[kb], bfr, acc[nt], 0, 0, 0);
            }
        }
        __syncthreads();
    }
#pragma unroll
    for (int nt = 0; nt < 2; nt++) {
        int col = nh * 32 + nt * 16 + l16;
#pragma unroll
        for (int r = 0; r < 4; r++) {
            int oc = ms * 16 + lq * 4 + r;
            if (oc < 27)
                om[(b * 27 + oc) * 4096 + h * 64 + col] = acc[nt][r];
        }
    }
}

// Deformable conv via MFMA. Block = (b,h) row, 4 waves; wave wv owns oc
// strip o0=wv*16 and all 64 pixel columns (4 N-tiles). Phase 0: per-pixel
// bilinear weights/indices (lane=w, taps clamped INDEPENDENTLY). Per
// K-chunk (32 channels): each wave samples 8 channels x 9 taps -> bf16
// short8 -> ds_write_b128, then 9x4 MFMAs against register-resident A-frags.
__global__ __launch_bounds__(256) void deform_mfma(
    const float* __restrict__ feat, const float* __restrict__ om_bias,
    const short* __restrict__ wd, const float* __restrict__ om,
    float* __restrict__ out)
{
    __shared__ short8 S[2304];
    const int b = blockIdx.x >> 6, h = blockIdx.x & 63;
    const int lane = threadIdx.x & 63;
    const int wv   = threadIdx.x >> 6;
    const int l16 = lane & 15, lq = lane >> 4;
    const int w = lane;
    const int hw = h * 64 + w;

    float W00[9], W01[9], W10[9], W11[9];
    int   A00[9], A01[9], A10[9], A11[9];
#pragma unroll
    for (int k = 0; k < 9; k++) {
        const float* p = om + b * 27 * 4096 + hw;
        float dy = om_bias[2 * k]     + p[(2 * k) * 4096];
        float dx = om_bias[2 * k + 1] + p[(2 * k + 1) * 4096];
        float mm = om_bias[18 + k]    + p[(18 + k) * 4096];
        mm = 1.f / (1.f + __expf(-mm));   // sigmoid(mask)
        float yy = (float)(h - 1 + k / 3) + dy;
        float xx = (float)(w - 1 + (k - (k / 3) * 3)) + dx;
        float fy = floorf(yy), fx = floorf(xx);
        int y0 = (int)fy, x0 = (int)fx;
        float wy = yy - fy, wx = xx - fx;
        bool vy0 = (y0 >= 0) & (y0 < 64);
        bool vy1 = (y0 >= -1) & (y0 < 63);
        bool vx0 = (x0 >= 0) & (x0 < 64);
        bool vx1 = (x0 >= -1) & (x0 < 63);
        float a0 = (1.f - wy) * mm, a1 = wy * mm;
        W00[k] = a0 * (1.f - wx) * (float)(vy0 & vx0);
        W01[k] = a0 * wx         * (float)(vy0 & vx1);
        W10[k] = a1 * (1.f - wx) * (float)(vy1 & vx0);
        W11[k] = a1 * wx         * (float)(vy1 & vx1);
        // clamp(y0+1), NOT clamp(y0)+1 (reference clips taps independently)
        int iy0 = min(max(y0, 0), 63),     ix0 = min(max(x0, 0), 63);
        int iy1 = min(max(y0 + 1, 0), 63), ix1 = min(max(x0 + 1, 0), 63);
        A00[k] = iy0 * 64 + ix0;  A01[k] = iy0 * 64 + ix1;
        A10[k] = iy1 * 64 + ix0;  A11[k] = iy1 * 64 + ix1;
    }

    float4v acc[4];
#pragma unroll
    for (int nt = 0; nt < 4; nt++) acc[nt] = (float4v){0.f, 0.f, 0.f, 0.f};

    for (int qh = 0; qh < 2; qh++) {          // K-chunk = 32 channels
        const float* sp = feat + (b * 64 + qh * 32 + wv * 8) * 4096;
#pragma unroll
        for (int t = 0; t < 9; t++) {
            short8 pk;
#pragma unroll
            for (int cc = 0; cc < 8; cc++) {
                const float* p = sp + cc * 4096;
                float s = W00[t] * p[A00[t]] + W01[t] * p[A01[t]]
                        + W10[t] * p[A10[t]] + W11[t] * p[A11[t]];
                pk[cc] = f2bf(s);
            }
            S[(t * 4 + wv) * 64 + w] = pk;
        }
        const short* Ap = wd + (wv * 16 + l16) * 576 + qh * 288 + lq * 8;
        short8 afr[9];
#pragma unroll
        for (int kb = 0; kb < 9; kb++)
            afr[kb] = *(const short8*)(Ap + kb * 32);
        __syncthreads();
#pragma unroll
        for (int kb = 0; kb < 9; kb++) {
#pragma unroll
            for (int nt = 0; nt < 4; nt++) {
                short8 bfr = S[(kb * 4 + lq) * 64 + (nt * 16 + l16)];
                acc[nt] = __builtin_amdgcn_mfma_f32_16x16x32_bf16(
                    afr[kb], bfr, acc[nt], 0, 0, 0);
            }
        }
        __syncthreads();
    }

#pragma unroll
    for (int nt = 0; nt < 4; nt++) {
        int col = nt * 16 + l16;
#pragma unroll
        for (int r = 0; r < 4; r++) {
            int o = wv * 16 + lq * 4 + r;
            out[(b * 64 + o) * 4096 + h * 64 + col] = acc[nt][r];
        }
    }
}

extern "C" void kernel_launch(void* const* d_in, const int* in_sizes, int n_in,
                              void* d_out, int out_size, void* d_ws, size_t ws_size,
                              hipStream_t stream)
{
    const float* feat      = (const float*)d_in[0];
    const float* deg       = (const float*)d_in[1];
    const float* weight    = (const float*)d_in[2];
    const float* om_weight = (const float*)d_in[3];
    const float* om_bias   = (const float*)d_in[4];
    float* out = (float*)d_out;
    short* wss = (short*)d_ws;
    float* wsf = (float*)d_ws;

    hipLaunchKernelGGL(prep_kernel,  dim3(288), dim3(256), 0, stream,
                       weight, om_weight, wss + WD_SHORT_OFF, wss + WO_SHORT_OFF);
    hipLaunchKernelGGL(omconv_mfma,  dim3(512), dim3(256), 0, stream,
                       feat, deg, wss + WO_SHORT_OFF, wsf + OM_FLOAT_OFF);
    hipLaunchKernelGGL(deform_mfma,  dim3(512), dim3(256), 0, stream,
                       feat, om_bias, wss + WD_SHORT_OFF, wsf + OM_FLOAT_OFF, out);
}

// Round 5
// 141.790 us; speedup vs baseline: 2.6509x; 1.2728x over previous
//
#include <hip/hip_runtime.h>
#include <math.h>

// B=8, C=64, H=W=64, O=64, K=3, KK=9, HW=4096
// MFMA formulation (bf16 in, fp32 acc), mfma_f32_16x16x32_bf16.
//
// omconv: om[b][oc][hw] = sum_k Wo[oc][k] * P[k][hw], K=1152 split in 4
//   quarters of 288; k = (cg>>5)*288 + t*32 + (cg&31). Grid split by source
//   half (feat / deg): two PARTIAL om buffers, summed in deform.
// deform: out[b][o][hw] = sum_k Wd[o][k] * S[k][hw], K=576;
//   k = t*64 + c. Grid split by pixel half (N-split, 32 cols per block).
//
// ws layout (bytes):
//   [0,      73728)  Wd bf16[64][576]   = weight[o][c][t],  k = t*64+c
//   [73728, 147456)  Wo bf16[32][1152]  = om_weight[oc][cg][t] (rows 27..31 = 0)
//   [147456, ...)    omp fp32[2][8][27][4096]  partial om (no bias)
#define WD_SHORT_OFF 0
#define WO_SHORT_OFF 36864
#define OM_FLOAT_OFF 36864   // in floats (byte 147456)

typedef short  short8  __attribute__((ext_vector_type(8)));
typedef float  float4v __attribute__((ext_vector_type(4)));

static __device__ __forceinline__ short f2bf(float f) {
    unsigned int u = __builtin_bit_cast(unsigned int, f);
    u += 0x7FFFu + ((u >> 16) & 1u);   // round-to-nearest-even
    return (short)(u >> 16);
}

__global__ __launch_bounds__(256) void prep_kernel(
    const float* __restrict__ weight, const float* __restrict__ om_weight,
    short* __restrict__ wd, short* __restrict__ wo)
{
    int idx = blockIdx.x * 256 + threadIdx.x;   // grid covers exactly 73728
    if (idx < 36864) {
        int o = idx / 576, r = idx % 576;
        int t = r >> 6, c = r & 63;             // k = t*64 + c
        wd[idx] = f2bf(weight[(o * 64 + c) * 9 + t]);
    } else {
        int e = idx - 36864;
        int ocp = e / 1152, r = e % 1152;
        int q = r / 288, rr = r % 288;
        int t = rr >> 5, cg = q * 32 + (rr & 31);
        wo[e] = (ocp < 27) ? f2bf(om_weight[(ocp * 128 + cg) * 9 + t])
                           : (short)0;
    }
}

// om conv partial. Block = (half, b, h): half selects feat or deg (2 K-chunks
// of 288). Staging: per (cc,ky) ONE coalesced row load; the 3 kx taps are
// lane shifts (__shfl) of it; rows with y out of range skipped uniformly.
__global__ __launch_bounds__(256) void omconv_mfma(
    const float* __restrict__ feat, const float* __restrict__ deg,
    const short* __restrict__ wo, float* __restrict__ omp)
{
    __shared__ short8 S[2304];                 // [g = t*4+wv][w]  36,864 B
    const int half = blockIdx.x >> 9;
    const int b = (blockIdx.x >> 6) & 7, h = blockIdx.x & 63;
    const int lane = threadIdx.x & 63;
    const int wv   = threadIdx.x >> 6;
    const int l16 = lane & 15, lq = lane >> 4;
    const int ms = wv & 1, nh = wv >> 1;
    const int w = lane;
    const float* src = half ? deg : feat;

    float4v acc[2];
    acc[0] = (float4v){0.f, 0.f, 0.f, 0.f};
    acc[1] = (float4v){0.f, 0.f, 0.f, 0.f};

    for (int qi = 0; qi < 2; qi++) {
        const int quarter = half * 2 + qi;
        const float* sp = src + (b * 64 + qi * 32 + wv * 8) * 4096;
        float rv[3][8];
#pragma unroll
        for (int ky = 0; ky < 3; ky++) {
            int y = h - 1 + ky;                // wave-uniform
            if (y >= 0 && y < 64) {
#pragma unroll
                for (int cc = 0; cc < 8; cc++)
                    rv[ky][cc] = sp[cc * 4096 + y * 64 + w];
            } else {
#pragma unroll
                for (int cc = 0; cc < 8; cc++) rv[ky][cc] = 0.f;
            }
        }
#pragma unroll
        for (int t = 0; t < 9; t++) {
            const int ky = t / 3, kx = t - ky * 3;
            short8 pk;
#pragma unroll
            for (int cc = 0; cc < 8; cc++) {
                float v = rv[ky][cc];
                float tap;
                if (kx == 0) { float u = __shfl_up(v, 1);  tap = (w == 0)  ? 0.f : u; }
                else if (kx == 2) { float d = __shfl_down(v, 1); tap = (w == 63) ? 0.f : d; }
                else tap = v;
                pk[cc] = f2bf(tap);
            }
            S[(t * 4 + wv) * 64 + w] = pk;
        }
        const short* Ap = wo + (ms * 16 + l16) * 1152 + quarter * 288 + lq * 8;
        short8 afr[9];
#pragma unroll
        for (int kb = 0; kb < 9; kb++)
            afr[kb] = *(const short8*)(Ap + kb * 32);
        __syncthreads();
#pragma unroll
        for (int kb = 0; kb < 9; kb++) {
#pragma unroll
            for (int nt = 0; nt < 2; nt++) {
                short8 bfr = S[(kb * 4 + lq) * 64 + (nh * 32 + nt * 16 + l16)];
                acc[nt] = __builtin_amdgcn_mfma_f32_16x16x32_bf16(
                    afr[kb], bfr, acc[nt], 0, 0, 0);
            }
        }
        __syncthreads();
    }
#pragma unroll
    for (int nt = 0; nt < 2; nt++) {
        int col = nh * 32 + nt * 16 + l16;
#pragma unroll
        for (int r = 0; r < 4; r++) {
            int oc = ms * 16 + lq * 4 + r;
            if (oc < 27)
                omp[((half * 8 + b) * 27 + oc) * 4096 + h * 64 + col] = acc[nt][r];
        }
    }
}

// Deformable conv, N-split. Block = (b, h, whalf): 32 pixel cols, full K=576.
// Staging thread (cpair = tid>>5, px = tid&31): t-outer loop computes bilinear
// coeffs inline (om prefetched into 27 regs, two partials + bias summed),
// then 8 channels x 4 taps -> bf16 short8 -> n-major LDS (pad row to 584
// shorts: writes & b128 reads both 2-way = conflict-free).
__global__ __launch_bounds__(256) void deform_mfma(
    const float* __restrict__ feat, const float* __restrict__ om_bias,
    const short* __restrict__ wd, const float* __restrict__ omp,
    float* __restrict__ out)
{
    __shared__ short8 S[32 * 73];              // [n][k8], 37,376 B
    const int b  = blockIdx.x >> 7;
    const int h  = (blockIdx.x >> 1) & 63;
    const int wh = blockIdx.x & 1;
    const int tid = threadIdx.x;
    const int lane = tid & 63, wv = tid >> 6;
    const int l16 = lane & 15, lq = lane >> 4;
    const int px = tid & 31, cpair = tid >> 5;
    const int w = wh * 32 + px;
    const int hw = h * 64 + w;

    // om = partial(feat-half) + partial(deg-half) + bias
    float omv[27];
    const float* p0 = omp + (b * 27) * 4096 + hw;
    const float* p1 = omp + ((8 + b) * 27) * 4096 + hw;
#pragma unroll
    for (int j = 0; j < 27; j++)
        omv[j] = p0[j * 4096] + p1[j * 4096] + om_bias[j];

    const float* pc = feat + (b * 64 + cpair * 8) * 4096;
#pragma unroll
    for (int t = 0; t < 9; t++) {
        const int ky = t / 3, kx = t - ky * 3;
        float dy = omv[2 * t], dx = omv[2 * t + 1];
        float mm = 1.f / (1.f + __expf(-omv[18 + t]));   // sigmoid(mask)
        float yy = (float)(h - 1 + ky) + dy;
        float xx = (float)(w - 1 + kx) + dx;
        float fy = floorf(yy), fx = floorf(xx);
        int y0 = (int)fy, x0 = (int)fx;
        float wy = yy - fy, wx = xx - fx;
        bool vy0 = (y0 >= 0) & (y0 < 64);
        bool vy1 = (y0 >= -1) & (y0 < 63);
        bool vx0 = (x0 >= 0) & (x0 < 64);
        bool vx1 = (x0 >= -1) & (x0 < 63);
        float a0 = (1.f - wy) * mm, a1 = wy * mm;
        float W00 = a0 * (1.f - wx) * (float)(vy0 & vx0);
        float W01 = a0 * wx         * (float)(vy0 & vx1);
        float W10 = a1 * (1.f - wx) * (float)(vy1 & vx0);
        float W11 = a1 * wx         * (float)(vy1 & vx1);
        // taps clamped INDEPENDENTLY: clamp(y0+1), not clamp(y0)+1
        int iy0 = min(max(y0, 0), 63),     ix0 = min(max(x0, 0), 63);
        int iy1 = min(max(y0 + 1, 0), 63), ix1 = min(max(x0 + 1, 0), 63);
        int A00 = iy0 * 64 + ix0, A01 = iy0 * 64 + ix1;
        int A10 = iy1 * 64 + ix0, A11 = iy1 * 64 + ix1;
        short8 pk;
#pragma unroll
        for (int cc = 0; cc < 8; cc++) {
            const float* p = pc + cc * 4096;
            float s = W00 * p[A00] + W01 * p[A01]
                    + W10 * p[A10] + W11 * p[A11];
            pk[cc] = f2bf(s);
        }
        S[px * 73 + t * 8 + cpair] = pk;
    }
    __syncthreads();

    float4v acc[2];
    acc[0] = (float4v){0.f, 0.f, 0.f, 0.f};
    acc[1] = (float4v){0.f, 0.f, 0.f, 0.f};
    const short* Ap = wd + (wv * 16 + l16) * 576 + lq * 8;
#pragma unroll
    for (int kb = 0; kb < 18; kb++) {
        short8 afr = *(const short8*)(Ap + kb * 32);
#pragma unroll
        for (int nt = 0; nt < 2; nt++) {
            short8 bfr = S[(nt * 16 + l16) * 73 + kb * 4 + lq];
            acc[nt] = __builtin_amdgcn_mfma_f32_16x16x32_bf16(
                afr, bfr, acc[nt], 0, 0, 0);
        }
    }

#pragma unroll
    for (int nt = 0; nt < 2; nt++) {
        int col = wh * 32 + nt * 16 + l16;
#pragma unroll
        for (int r = 0; r < 4; r++) {
            int o = wv * 16 + lq * 4 + r;
            out[(b * 64 + o) * 4096 + h * 64 + col] = acc[nt][r];
        }
    }
}

extern "C" void kernel_launch(void* const* d_in, const int* in_sizes, int n_in,
                              void* d_out, int out_size, void* d_ws, size_t ws_size,
                              hipStream_t stream)
{
    const float* feat      = (const float*)d_in[0];
    const float* deg       = (const float*)d_in[1];
    const float* weight    = (const float*)d_in[2];
    const float* om_weight = (const float*)d_in[3];
    const float* om_bias   = (const float*)d_in[4];
    float* out = (float*)d_out;
    short* wss = (short*)d_ws;
    float* wsf = (float*)d_ws;

    hipLaunchKernelGGL(prep_kernel,  dim3(288),  dim3(256), 0, stream,
                       weight, om_weight, wss + WD_SHORT_OFF, wss + WO_SHORT_OFF);
    hipLaunchKernelGGL(omconv_mfma,  dim3(1024), dim3(256), 0, stream,
                       feat, deg, wss + WO_SHORT_OFF, wsf + OM_FLOAT_OFF);
    hipLaunchKernelGGL(deform_mfma,  dim3(1024), dim3(256), 0, stream,
                       feat, om_bias, wss + WD_SHORT_OFF, wsf + OM_FLOAT_OFF, out);
}

// Round 6
// 113.198 us; speedup vs baseline: 3.3205x; 1.2526x over previous
//
#include <hip/hip_runtime.h>
#include <math.h>

// B=8, C=64, H=W=64, O=64, K=3, KK=9, HW=4096
// Fully fused formulation, mfma_f32_16x16x32_bf16 (bf16 in, fp32 acc).
// One wave owns 16 pixels (one h-row segment) and computes om (K=1152) then
// the deformable conv (K=576) with NO cross-wave communication.
// Operand orientation (HW-validated in rounds 4/5):
//   A = weights:  lane(l16,lq) holds W[m = tile*16+l16][k = step*32+lq*8+j]
//   B = samples:  lane(l16,lq) holds S[k = step*32+lq*8+j][n = px(l16)]
//   C/D: col(=px) = lane&15, row(=m) = (lane>>4)*4 + reg
//
// ws layout (shorts):
//   [0,     36864)  wd_pk : Wd A-frag-packed, idx=((ks*4+lq)*64+o)*8+j,
//                   ks=t*2+qh (18), k=t*64+qh*32+lq*8+j -> weight[o][c][t]
//   [36864, 73728)  wo_pk : Wo A-frag-packed, idx=((ks2*4+lq)*32+oc)*8+j,
//                   ks2=quarter*9+t (36), cg=quarter*32+lq*8+j; oc>=27 -> 0
//   [73728, 73728+4194304)  catT bf16[b][hw][128]  (feat c0..63, deg c64..127)
#define WO_PK_OFF 36864
#define CATT_OFF  73728

typedef short  short8  __attribute__((ext_vector_type(8)));
typedef float  float4v __attribute__((ext_vector_type(4)));

static __device__ __forceinline__ short f2bf(float f) {
    unsigned int u = __builtin_bit_cast(unsigned int, f);
    u += 0x7FFFu + ((u >> 16) & 1u);   // round-to-nearest-even
    return (short)(u >> 16);
}
static __device__ __forceinline__ float bf2f(unsigned short u) {
    return __builtin_bit_cast(float, (unsigned int)u << 16);
}

__global__ __launch_bounds__(256) void prep_w(
    const float* __restrict__ weight, const float* __restrict__ om_weight,
    short* __restrict__ wd_pk, short* __restrict__ wo_pk)
{
    int idx = blockIdx.x * 256 + threadIdx.x;   // grid covers exactly 73728
    if (idx < 36864) {
        int j = idx & 7, o = (idx >> 3) & 63, lq = (idx >> 9) & 3, ks = idx >> 11;
        int t = ks >> 1, c = (ks & 1) * 32 + lq * 8 + j;
        wd_pk[idx] = f2bf(weight[(o * 64 + c) * 9 + t]);
    } else {
        int e = idx - 36864;
        int j = e & 7, oc = (e >> 3) & 31, lq = (e >> 8) & 3, ks2 = e >> 10;
        int quarter = ks2 / 9, t = ks2 - quarter * 9;
        int cg = quarter * 32 + lq * 8 + j;
        wo_pk[e] = (oc < 27) ? f2bf(om_weight[(oc * 128 + cg) * 9 + t])
                             : (short)0;
    }
}

// catT[b][hw][128] bf16 from NCHW fp32 feat/deg via LDS transpose.
// Block = (b,h): 64 pixels x 128 channels. Row pad 136 shorts (16B-aligned
// b128 reads, ~2-way banks).
__global__ __launch_bounds__(256) void transpose_kernel(
    const float* __restrict__ feat, const float* __restrict__ deg,
    unsigned short* __restrict__ catT)
{
    __shared__ unsigned short T[64 * 136];     // 17,408 B
    const int b = blockIdx.x >> 6, h = blockIdx.x & 63;
    const int tid = threadIdx.x;
    const int lane = tid & 63, wv = tid >> 6;
#pragma unroll
    for (int cc = 0; cc < 32; cc++) {
        int c = wv * 32 + cc;                  // wave-uniform
        const float* src = (c < 64)
            ? (feat + (size_t)(b * 64 + c) * 4096)
            : (deg  + (size_t)(b * 64 + (c - 64)) * 4096);
        T[lane * 136 + c] = (unsigned short)f2bf(src[h * 64 + lane]);
    }
    __syncthreads();
    const int px = tid >> 2, seg = tid & 3;
    unsigned short* dst = catT + (size_t)(b * 4096 + h * 64 + px) * 128 + seg * 32;
#pragma unroll
    for (int j = 0; j < 4; j++)
        *(uint4*)(dst + j * 8) = *(const uint4*)&T[px * 136 + seg * 32 + j * 8];
}

// The fused kernel. gw = wave id in [0,2048): b = gw>>8, 16-px tile = gw&255.
// Phase 1 (omconv): 36 K-steps, 2 MFMAs each. Phase 2: wave-private LDS
// transpose C-layout -> per-pixel omv[27] (+bias), one barrier. Phase 3
// (deform): 9 taps x 2 ch-halves: bilinear on bf16 catT, pack, 4 MFMAs.
__global__ __launch_bounds__(256) void fused_kernel(
    const unsigned short* __restrict__ catT, const short* __restrict__ wd_pk,
    const short* __restrict__ wo_pk, const float* __restrict__ om_bias,
    float* __restrict__ out)
{
    __shared__ float T[4 * 16 * 36];           // 9,216 B (per-wave 16x36)
    const int tid = threadIdx.x;
    const int lane = tid & 63, wv = tid >> 6;
    const int l16 = lane & 15, lq = lane >> 4;
    const int gw = blockIdx.x * 4 + wv;
    const int b = gw >> 8, tile = gw & 255;
    const int h = tile >> 2, w0 = (tile & 3) << 4;
    const int pxx = w0 + l16;                  // this lane's pixel x
    const unsigned short* cb = catT + (size_t)b * 4096 * 128;

    // ---------------- phase 1: om conv ----------------
    float4v oacc0 = {0.f, 0.f, 0.f, 0.f};
    float4v oacc1 = {0.f, 0.f, 0.f, 0.f};
    const short8 zf = {0, 0, 0, 0, 0, 0, 0, 0};
#pragma unroll
    for (int quarter = 0; quarter < 4; quarter++) {
#pragma unroll
        for (int t = 0; t < 9; t++) {
            const int ky = t / 3, kx = t - ky * 3;
            const int yy = h - 1 + ky;         // wave-uniform
            if (yy >= 0 && yy <= 63) {
                int xx = pxx - 1 + kx;
                bool okx = (xx >= 0) & (xx <= 63);
                int xc = min(max(xx, 0), 63);
                short8 bfr = *(const short8*)(cb + (yy * 64 + xc) * 128
                                                 + quarter * 32 + lq * 8);
                bfr = okx ? bfr : zf;
                const short8* Ap = (const short8*)(wo_pk
                    + (size_t)((quarter * 9 + t) * 4 + lq) * 256);
                oacc0 = __builtin_amdgcn_mfma_f32_16x16x32_bf16(
                    Ap[l16], bfr, oacc0, 0, 0, 0);
                oacc1 = __builtin_amdgcn_mfma_f32_16x16x32_bf16(
                    Ap[16 + l16], bfr, oacc1, 0, 0, 0);
            }
        }
    }

    // ------- phase 2: wave-private transpose -> omv[27] -------
    float* Tw = T + wv * 576;
#pragma unroll
    for (int r = 0; r < 4; r++) {
        Tw[l16 * 36 + lq * 4 + r]      = oacc0[r];   // oc = lq*4+r
        Tw[l16 * 36 + 16 + lq * 4 + r] = oacc1[r];   // oc = 16+lq*4+r
    }
    __syncthreads();                            // orders intra-wave LDS w->r
    float omv[28];
#pragma unroll
    for (int jj = 0; jj < 7; jj++)
        *(float4v*)&omv[jj * 4] = *(const float4v*)&Tw[l16 * 36 + jj * 4];
#pragma unroll
    for (int j = 0; j < 27; j++) omv[j] += om_bias[j];

    // ---------------- phase 3: deformable conv ----------------
    float4v acc[4];
#pragma unroll
    for (int mt = 0; mt < 4; mt++) acc[mt] = (float4v){0.f, 0.f, 0.f, 0.f};
#pragma unroll
    for (int t = 0; t < 9; t++) {
        const int ky = t / 3, kx = t - ky * 3;
        float dy = omv[2 * t], dx = omv[2 * t + 1];
        float mm = 1.f / (1.f + __expf(-omv[18 + t]));   // sigmoid(mask)
        float yf = (float)(h - 1 + ky) + dy;
        float xf = (float)(pxx - 1 + kx) + dx;
        float fy = floorf(yf), fx = floorf(xf);
        int y0 = (int)fy, x0 = (int)fx;
        float wy = yf - fy, wx = xf - fx;
        bool vy0 = (y0 >= 0) & (y0 < 64);
        bool vy1 = (y0 >= -1) & (y0 < 63);
        bool vx0 = (x0 >= 0) & (x0 < 64);
        bool vx1 = (x0 >= -1) & (x0 < 63);
        float a0 = (1.f - wy) * mm, a1 = wy * mm;
        float W00 = a0 * (1.f - wx) * (float)(vy0 & vx0);
        float W01 = a0 * wx         * (float)(vy0 & vx1);
        float W10 = a1 * (1.f - wx) * (float)(vy1 & vx0);
        float W11 = a1 * wx         * (float)(vy1 & vx1);
        // taps clamped INDEPENDENTLY: clamp(y0+1), not clamp(y0)+1
        int iy0 = min(max(y0, 0), 63),     ix0 = min(max(x0, 0), 63);
        int iy1 = min(max(y0 + 1, 0), 63), ix1 = min(max(x0 + 1, 0), 63);
        int O00 = (iy0 * 64 + ix0) * 128, O01 = (iy0 * 64 + ix1) * 128;
        int O10 = (iy1 * 64 + ix0) * 128, O11 = (iy1 * 64 + ix1) * 128;
#pragma unroll
        for (int qh = 0; qh < 2; qh++) {
            const int cho = qh * 32 + lq * 8;    // feat channels only (<64)
            short8 c00 = *(const short8*)(cb + O00 + cho);
            short8 c01 = *(const short8*)(cb + O01 + cho);
            short8 c10 = *(const short8*)(cb + O10 + cho);
            short8 c11 = *(const short8*)(cb + O11 + cho);
            short8 bfr;
#pragma unroll
            for (int j = 0; j < 8; j++) {
                float s = W00 * bf2f((unsigned short)c00[j])
                        + W01 * bf2f((unsigned short)c01[j])
                        + W10 * bf2f((unsigned short)c10[j])
                        + W11 * bf2f((unsigned short)c11[j]);
                bfr[j] = f2bf(s);
            }
            const short8* Dp = (const short8*)(wd_pk
                + (size_t)((t * 2 + qh) * 4 + lq) * 512);
            acc[0] = __builtin_amdgcn_mfma_f32_16x16x32_bf16(
                Dp[l16], bfr, acc[0], 0, 0, 0);
            acc[1] = __builtin_amdgcn_mfma_f32_16x16x32_bf16(
                Dp[16 + l16], bfr, acc[1], 0, 0, 0);
            acc[2] = __builtin_amdgcn_mfma_f32_16x16x32_bf16(
                Dp[32 + l16], bfr, acc[2], 0, 0, 0);
            acc[3] = __builtin_amdgcn_mfma_f32_16x16x32_bf16(
                Dp[48 + l16], bfr, acc[3], 0, 0, 0);
        }
    }

    // store: o = mt*16 + lq*4 + r, px = w0 + l16 (4-seg coalesced)
    float* ob = out + (size_t)(b * 64) * 4096 + h * 64 + w0 + l16;
#pragma unroll
    for (int mt = 0; mt < 4; mt++)
#pragma unroll
        for (int r = 0; r < 4; r++)
            ob[(mt * 16 + lq * 4 + r) * 4096] = acc[mt][r];
}

extern "C" void kernel_launch(void* const* d_in, const int* in_sizes, int n_in,
                              void* d_out, int out_size, void* d_ws, size_t ws_size,
                              hipStream_t stream)
{
    const float* feat      = (const float*)d_in[0];
    const float* deg       = (const float*)d_in[1];
    const float* weight    = (const float*)d_in[2];
    const float* om_weight = (const float*)d_in[3];
    const float* om_bias   = (const float*)d_in[4];
    float* out = (float*)d_out;
    short* wss = (short*)d_ws;
    unsigned short* catT = (unsigned short*)(wss + CATT_OFF);

    hipLaunchKernelGGL(prep_w,           dim3(288), dim3(256), 0, stream,
                       weight, om_weight, wss, wss + WO_PK_OFF);
    hipLaunchKernelGGL(transpose_kernel, dim3(512), dim3(256), 0, stream,
                       feat, deg, catT);
    hipLaunchKernelGGL(fused_kernel,     dim3(512), dim3(256), 0, stream,
                       catT, wss, wss + WO_PK_OFF, om_bias, out);
}